// Round 16
// baseline (452.745 us; speedup 1.0000x reference)
//
#include <hip/hip_runtime.h>
#include <hip/hip_bf16.h>
#include <stdint.h>

typedef unsigned short u16;
typedef __attribute__((ext_vector_type(8))) short short8;
typedef __attribute__((ext_vector_type(4))) float f32x4;

#define B_N   2
#define S_LEN 2048
#define D_MOD 2048
#define N_HQ  16
#define N_HKV 4
#define N_HD  128
// G = 4

__device__ __forceinline__ u16 f2b(float f) {
  union { float f; uint32_t u; } v; v.f = f;
  uint32_t r = v.u + 0x7fffu + ((v.u >> 16) & 1u);
  return (u16)(r >> 16);
}

// round-half-up bf16 pair pack: hi16(a+0x8000) in [15:0], hi16(b+0x8000) in [31:16]
__device__ __forceinline__ uint32_t pack2_rhu(float a, float b) {
  union { float f; uint32_t u; } va, vb;
  va.f = a; vb.f = b;
  return __builtin_amdgcn_perm(vb.u + 0x8000u, va.u + 0x8000u, 0x07060302u);
}

__device__ __forceinline__ void gload_lds16(const void* g, void* l) {
  __builtin_amdgcn_global_load_lds((__attribute__((address_space(1))) void*)g,
                                   (__attribute__((address_space(3))) void*)l,
                                   16, 0, 0);
}

// ------------- fused pre-pass: x f32->bf16  +  4 weight transposes -------------
__global__ void k_pre(const float* __restrict__ x, u16* __restrict__ x_bf,
                      const float* __restrict__ Wq, const float* __restrict__ Wk,
                      const float* __restrict__ Wv, const float* __restrict__ Wo,
                      u16* __restrict__ Wqt, u16* __restrict__ Wkt,
                      u16* __restrict__ Wvt, u16* __restrict__ Wot) {
  const int bid = blockIdx.x;
  if (bid < 4096) {
    int i = (bid * 256 + threadIdx.x) * 8;
    float4 a = *(const float4*)(x + i);
    float4 b = *(const float4*)(x + i + 4);
    short8 o;
    o[0] = (short)f2b(a.x); o[1] = (short)f2b(a.y);
    o[2] = (short)f2b(a.z); o[3] = (short)f2b(a.w);
    o[4] = (short)f2b(b.x); o[5] = (short)f2b(b.y);
    o[6] = (short)f2b(b.z); o[7] = (short)f2b(b.w);
    *(short8*)(x_bf + i) = o;
    return;
  }
  __shared__ float tile[32][33];
  const int idx = bid - 4096;          // 0..10239
  const int cb = idx % 160;
  const int k0 = (idx / 160) * 32;
  const float* W; u16* Wt; int N, n0;
  if (cb < 64)      { W = Wq; Wt = Wqt; N = 2048; n0 = cb * 32; }
  else if (cb < 80) { W = Wk; Wt = Wkt; N = 512;  n0 = (cb - 64) * 32; }
  else if (cb < 96) { W = Wv; Wt = Wvt; N = 512;  n0 = (cb - 80) * 32; }
  else              { W = Wo; Wt = Wot; N = 2048; n0 = (cb - 96) * 32; }
  const int tx = threadIdx.x & 31, ty = threadIdx.x >> 5;
#pragma unroll
  for (int i = 0; i < 4; i++) {
    int r = ty + i * 8;
    tile[r][tx] = W[(size_t)(k0 + r) * N + n0 + tx];
  }
  __syncthreads();
#pragma unroll
  for (int i = 0; i < 4; i++) {
    int r = ty + i * 8;
    Wt[(size_t)(n0 + r) * 2048 + k0 + tx] = f2b(tile[tx][r]);
  }
}

// ------------- fused QKV GEMM (128x128 tiles, T2 XOR-swizzled LDS) -------------
__global__ __launch_bounds__(256, 3) void k_gemm_qkv(
    const u16* __restrict__ A,
    const u16* __restrict__ Wqt, const u16* __restrict__ Wkt, const u16* __restrict__ Wvt,
    u16* __restrict__ Qout, u16* __restrict__ Kout, u16* __restrict__ Vt,
    float qscale)
{
  __shared__ __attribute__((aligned(16))) u16 lA[128 * 64];
  __shared__ __attribute__((aligned(16))) u16 lB[128 * 64];
  const int K = D_MOD;
  const int tid = threadIdx.x;
  const int lane = tid & 63, w = tid >> 6;
  const int wr = w >> 1, wc = w & 1;
  const int lin = blockIdx.y * 24 + blockIdx.x;
  const int swz = (lin & 7) * 96 + (lin >> 3);
  const int bx = swz % 24;
  const int kind = bx < 16 ? 0 : (bx < 20 ? 1 : 2);
  const int bcol = (kind == 0 ? bx : (bx & 3)) * 128;
  const u16* Bt = kind == 0 ? Wqt : (kind == 1 ? Wkt : Wvt);
  const int brow = (swz / 24) * 128;
  const int lrow = lane >> 3;
  const int l15 = lane & 15, lg = lane >> 4;
  const int l7a = l15 & 7;

  f32x4 acc[4][4] = {};

  for (int kt = 0; kt < K; kt += 64) {
#pragma unroll
    for (int i = 0; i < 4; i++) {
      int row = (w * 4 + i) * 8 + lrow;
      int ch = (lane & 7) ^ (row & 7);
      gload_lds16(A + (size_t)(brow + row) * K + kt + ch * 8, &lA[(w * 4 + i) * 512]);
      gload_lds16(Bt + (size_t)(bcol + row) * K + kt + ch * 8, &lB[(w * 4 + i) * 512]);
    }
    __syncthreads();
#pragma unroll
    for (int kk = 0; kk < 2; kk++) {
      short8 af[4], bf[4];
#pragma unroll
      for (int m = 0; m < 4; m++)
        af[m] = *(const short8*)&lA[(wr * 64 + m * 16 + l15) * 64 + (((kk * 4 + lg) ^ l7a) * 8)];
#pragma unroll
      for (int n = 0; n < 4; n++)
        bf[n] = *(const short8*)&lB[(wc * 64 + n * 16 + l15) * 64 + (((kk * 4 + lg) ^ l7a) * 8)];
#pragma unroll
      for (int m = 0; m < 4; m++)
#pragma unroll
        for (int n = 0; n < 4; n++)
          acc[m][n] = __builtin_amdgcn_mfma_f32_16x16x32_bf16(af[m], bf[n], acc[m][n], 0, 0, 0);
    }
    __syncthreads();
  }

#pragma unroll
  for (int m = 0; m < 4; m++) {
#pragma unroll
    for (int n = 0; n < 4; n++) {
#pragma unroll
      for (int r = 0; r < 4; r++) {
        float v = acc[m][n][r];
        int row = brow + wr * 64 + m * 16 + lg * 4 + r;
        int col = bcol + wc * 64 + n * 16 + l15;
        if (kind == 0) {
          Qout[(size_t)row * (N_HQ * N_HD) + col] = f2b(v * qscale);
        } else if (kind == 1) {
          Kout[(size_t)row * (N_HKV * N_HD) + col] = f2b(v);
        } else { // V^T scatter (natural s order): row = token, col = hkv*128+d
          int bb = row >> 11, s = row & 2047;
          int hkv = col >> 7, d = col & 127;
          Vt[((size_t)((bb * N_HKV + hkv) * N_HD + d)) * S_LEN + s] = f2b(v);
        }
      }
    }
  }
}

// ---------------- O-proj GEMM (128x128 tiles, T2 XOR-swizzled LDS) ----------------
__global__ __launch_bounds__(256, 3) void k_gemm_o(
    const u16* __restrict__ A, const u16* __restrict__ Bt,
    float* __restrict__ Cout, const float* __restrict__ bias,
    int M, int N, int K)
{
  __shared__ __attribute__((aligned(16))) u16 lA[128 * 64];
  __shared__ __attribute__((aligned(16))) u16 lB[128 * 64];
  const int tid = threadIdx.x;
  const int lane = tid & 63, w = tid >> 6;
  const int wr = w >> 1, wc = w & 1;
  const int lin = blockIdx.y * 16 + blockIdx.x;
  const int swz = (lin & 7) * 64 + (lin >> 3);
  const int brow = (swz / 16) * 128, bcol = (swz % 16) * 128;
  const int lrow = lane >> 3;
  const int l15 = lane & 15, lg = lane >> 4;
  const int l7a = l15 & 7;

  f32x4 acc[4][4] = {};

  for (int kt = 0; kt < K; kt += 64) {
#pragma unroll
    for (int i = 0; i < 4; i++) {
      int row = (w * 4 + i) * 8 + lrow;
      int ch = (lane & 7) ^ (row & 7);
      gload_lds16(A + (size_t)(brow + row) * K + kt + ch * 8, &lA[(w * 4 + i) * 512]);
      gload_lds16(Bt + (size_t)(bcol + row) * K + kt + ch * 8, &lB[(w * 4 + i) * 512]);
    }
    __syncthreads();
#pragma unroll
    for (int kk = 0; kk < 2; kk++) {
      short8 af[4], bf[4];
#pragma unroll
      for (int m = 0; m < 4; m++)
        af[m] = *(const short8*)&lA[(wr * 64 + m * 16 + l15) * 64 + (((kk * 4 + lg) ^ l7a) * 8)];
#pragma unroll
      for (int n = 0; n < 4; n++)
        bf[n] = *(const short8*)&lB[(wc * 64 + n * 16 + l15) * 64 + (((kk * 4 + lg) ^ l7a) * 8)];
#pragma unroll
      for (int m = 0; m < 4; m++)
#pragma unroll
        for (int n = 0; n < 4; n++)
          acc[m][n] = __builtin_amdgcn_mfma_f32_16x16x32_bf16(af[m], bf[n], acc[m][n], 0, 0, 0);
    }
    __syncthreads();
  }

#pragma unroll
  for (int m = 0; m < 4; m++) {
#pragma unroll
    for (int n = 0; n < 4; n++) {
#pragma unroll
      for (int r = 0; r < 4; r++) {
        int row = brow + wr * 64 + m * 16 + lg * 4 + r;
        int col = bcol + wc * 64 + n * 16 + l15;
        Cout[(size_t)row * N + col] = acc[m][n][r] + bias[col];
      }
    }
  }
}

// ---------------- flash attention v10: T14 single-buffer, 4 blocks/CU ----------------
// 32KB LDS (no dbuf, no p_lds) -> 4 blocks/CU (VGPR-capped at 128 via launch_bounds(256,4)).
// Round: LOADREGS(next) at top (HBM latency hides under compute); compute from LDS;
// barrier A (reads done); WRITEREGS (vmcnt auto-waits); barrier B (tile visible).
// Layouts identical to v9 (linear LDS dest, pre-swizzled source, sigma-keyed K).
__global__ __launch_bounds__(256, 4) void k_attn(
    const u16* __restrict__ Q,   // [B*S, HQ*HD], pre-scaled by SCALE*log2e
    const u16* __restrict__ Kb,  // [B*S, HKV*HD]
    const u16* __restrict__ Vt,  // [B, HKV, HD, S] natural s order
    u16* __restrict__ O)         // [B*S, HQ*HD]
{
  __shared__ __attribute__((aligned(16))) u16 lK[64 * 128];   // 16KB
  __shared__ __attribute__((aligned(16))) u16 lV[128 * 64];   // 16KB (V^T)
  const int lane = threadIdx.x & 63, w = threadIdx.x >> 6;
  const int lin = blockIdx.z * 256 + blockIdx.y * 16 + blockIdx.x;
  const int swz = (lin & 7) * 64 + (lin >> 3);
  const int qt = swz & 15, h = (swz >> 4) & 15, b = swz >> 8;
  const int hkv = h >> 2;
  const int qbase = qt * 128 + w * 32;
  const int l15 = lane & 15, lg = lane >> 4;
  const int l7 = lane & 7, l3 = lane >> 3;

  const u16* kbp = Kb + (size_t)(b * S_LEN) * (N_HKV * N_HD) + hkv * N_HD;
  const u16* vbp = Vt + (size_t)((b * N_HKV + hkv) * N_HD) * S_LEN;

  short8 qf[2][4];
#pragma unroll
  for (int s = 0; s < 2; s++) {
    const u16* qptr = Q + (size_t)(b * S_LEN + qbase + s * 16 + l15) * (N_HQ * N_HD) + h * N_HD + lg * 8;
#pragma unroll
    for (int kk = 0; kk < 4; kk++) qf[s][kk] = *(const short8*)(qptr + kk * 32);
  }

  f32x4 acc_o[2][8] = {};
  f32x4 acc_ls[2] = {};
  short8 vone;
#pragma unroll
  for (int j = 0; j < 8; j++) vone[j] = (short)0x3F80; // bf16 1.0

  short8 kreg[4], vreg[4];

#define LOADREGS(ktv) do {                                                           \
    _Pragma("unroll")                                                                \
    for (int i = 0; i < 4; i++) {                                                    \
      int kr = i * 16 + w * 4 + lg;                                                  \
      int sx = (kr & 3) ^ (((kr >> 3) & 3) << 1);                                    \
      kreg[i] = *(const short8*)(kbp + (size_t)((ktv) + kr) * (N_HKV * N_HD) + (l15 ^ sx) * 8); \
      int vr = i * 32 + w * 8 + l3;                                                  \
      vreg[i] = *(const short8*)(vbp + (size_t)vr * S_LEN + (ktv) + (l7 ^ (vr & 7)) * 8);       \
    } } while (0)

#define WRITEREGS() do {                                                             \
    _Pragma("unroll")                                                                \
    for (int i = 0; i < 4; i++) {                                                    \
      *(short8*)&lK[(i * 16 + w * 4) * 128 + lane * 8] = kreg[i];                    \
      *(short8*)&lV[(i * 32 + w * 8) * 64 + lane * 8] = vreg[i];                     \
    } } while (0)

  LOADREGS(0);
  WRITEREGS();
  __syncthreads();

  const int sxr = (l15 & 3) ^ (((l15 >> 2) & 3) << 1); // sxk(sigma_nf(l15)) (nf-indep)
  const int NT = S_LEN / 64;
  for (int it = 0; it < NT; ++it) {
    if (it + 1 < NT) LOADREGS((it + 1) * 64);   // issue early; lands during compute

    // ---- sc = K sigma-rows x Q  -> D[key][q]  (kf read once, shared by both q-sets) ----
    f32x4 sc[2][4] = {};
    __builtin_amdgcn_s_setprio(1);
#pragma unroll
    for (int nf = 0; nf < 4; nf++) {
      int krow = (nf >> 1) * 32 + ((l15 >> 2) * 8) + ((nf & 1) * 4) + (l15 & 3);
      const u16* kro = &lK[krow * 128];
#pragma unroll
      for (int kk = 0; kk < 4; kk++) {
        short8 kf = *(const short8*)&kro[(((kk * 4 + lg) ^ sxr) * 8)];
#pragma unroll
        for (int s = 0; s < 2; s++)
          sc[s][nf] = __builtin_amdgcn_mfma_f32_16x16x32_bf16(kf, qf[s][kk], sc[s][nf], 0, 0, 0);
      }
    }
    __builtin_amdgcn_s_setprio(0);

    // ---- P = exp2(sc), packed in-lane via round-half-up + v_perm ----
    short8 pf[2][2];
#pragma unroll
    for (int s = 0; s < 2; s++)
#pragma unroll
      for (int p2 = 0; p2 < 2; p2++) {
        union { short8 s8; uint32_t w4[4]; } u;
#pragma unroll
        for (int j = 0; j < 4; j++) {
          float lo = __builtin_amdgcn_exp2f(sc[s][p2 * 2 + (j >> 1)][(j & 1) * 2]);
          float hi = __builtin_amdgcn_exp2f(sc[s][p2 * 2 + (j >> 1)][(j & 1) * 2 + 1]);
          u.w4[j] = pack2_rhu(lo, hi);
        }
        pf[s][p2] = u.s8;
      }

    // ---- rowsum + PV (setprio cluster) ----
    __builtin_amdgcn_s_setprio(1);
#pragma unroll
    for (int s = 0; s < 2; s++)
#pragma unroll
      for (int p2 = 0; p2 < 2; p2++)
        acc_ls[s] = __builtin_amdgcn_mfma_f32_16x16x32_bf16(pf[s][p2], vone, acc_ls[s], 0, 0, 0);

#pragma unroll
    for (int nc = 0; nc < 8; nc++) {
      int vrow = nc * 16 + l15;
      const u16* vro = &lV[vrow * 64];
#pragma unroll
      for (int p2 = 0; p2 < 2; p2++) {
        short8 vf = *(const short8*)&vro[(((p2 * 4 + lg) ^ (vrow & 7)) * 8)];
#pragma unroll
        for (int s = 0; s < 2; s++)
          acc_o[s][nc] = __builtin_amdgcn_mfma_f32_16x16x32_bf16(pf[s][p2], vf, acc_o[s][nc], 0, 0, 0);
      }
    }
    __builtin_amdgcn_s_setprio(0);

    __syncthreads();                 // A: all waves done reading lK/lV
    if (it + 1 < NT) WRITEREGS();    // vmcnt waits auto-inserted on reg use
    __syncthreads();                 // B: new tile visible to all waves
  }
#undef LOADREGS
#undef WRITEREGS

#pragma unroll
  for (int s = 0; s < 2; s++)
#pragma unroll
    for (int r = 0; r < 4; r++) {
      float inv = 1.f / acc_ls[s][r];
      size_t row = (size_t)(b * S_LEN + qbase + s * 16 + lg * 4 + r);
#pragma unroll
      for (int nc = 0; nc < 8; nc++)
        O[row * (N_HQ * N_HD) + h * N_HD + nc * 16 + l15] = f2b(acc_o[s][nc][r] * inv);
    }
}

// ---------------- launcher ----------------
extern "C" void kernel_launch(void* const* d_in, const int* in_sizes, int n_in,
                              void* d_out, int out_size, void* d_ws, size_t ws_size,
                              hipStream_t stream) {
  const float* x  = (const float*)d_in[0];
  const float* Wq = (const float*)d_in[1];
  const float* Wk = (const float*)d_in[2];
  const float* Wv = (const float*)d_in[3];
  const float* Wo = (const float*)d_in[4];
  const float* bo = (const float*)d_in[5];
  float* out = (float*)d_out;

  char* ws = (char*)d_ws;
  u16* x_bf = (u16*)(ws + 0);           // 8388608 elems
  u16* Wqt  = (u16*)(ws + 16777216);    // 4194304 elems
  u16* Wkt  = (u16*)(ws + 25165824);    // 1048576 elems
  u16* Wvt  = (u16*)(ws + 27262976);    // 1048576 elems
  u16* Wot  = (u16*)(ws + 29360128);    // 4194304 elems
  u16* Qb   = (u16*)(ws + 37748736);    // 8388608 elems
  u16* Kbuf = (u16*)(ws + 54525952);    // 2097152 elems
  u16* Vt   = (u16*)(ws + 58720256);    // 2097152 elems
  u16* AO   = (u16*)(ws + 0);           // 8388608 elems (reuse of x_bf)

  // fused pre-pass: x convert (4096 blocks) + weight transposes (10240 blocks)
  k_pre<<<14336, 256, 0, stream>>>(x, x_bf, Wq, Wk, Wv, Wo, Wqt, Wkt, Wvt, Wot);

  const float qscale = 1.4426950408889634f / sqrtf((float)N_HD); // SCALE * log2(e)

  // fused Q/K/V projections (128x128 tiles, 3 blocks/CU)
  k_gemm_qkv<<<dim3(24, 32), 256, 0, stream>>>(
      x_bf, Wqt, Wkt, Wvt, Qb, Kbuf, Vt, qscale);

  // attention
  k_attn<<<dim3(S_LEN / 128, N_HQ, B_N), 256, 0, stream>>>(Qb, Kbuf, Vt, AO);

  // out = AO @ Wo + bo  (f32)
  k_gemm_o<<<dim3(16, 32), 256, 0, stream>>>(
      AO, Wot, out, bo, B_N * S_LEN, D_MOD, N_HQ * N_HD);
}

// Round 17
// 266.136 us; speedup vs baseline: 1.7012x; 1.7012x over previous
//
#include <hip/hip_runtime.h>
#include <hip/hip_bf16.h>
#include <stdint.h>

typedef unsigned short u16;
typedef __attribute__((ext_vector_type(8))) short short8;
typedef __attribute__((ext_vector_type(4))) float f32x4;

#define B_N   2
#define S_LEN 2048
#define D_MOD 2048
#define N_HQ  16
#define N_HKV 4
#define N_HD  128
// G = 4

__device__ __forceinline__ u16 f2b(float f) {
  union { float f; uint32_t u; } v; v.f = f;
  uint32_t r = v.u + 0x7fffu + ((v.u >> 16) & 1u);
  return (u16)(r >> 16);
}

// round-half-up bf16 pair pack: hi16(a+0x8000) in [15:0], hi16(b+0x8000) in [31:16]
__device__ __forceinline__ uint32_t pack2_rhu(float a, float b) {
  union { float f; uint32_t u; } va, vb;
  va.f = a; vb.f = b;
  return __builtin_amdgcn_perm(vb.u + 0x8000u, va.u + 0x8000u, 0x07060302u);
}

__device__ __forceinline__ void gload_lds16(const void* g, void* l) {
  __builtin_amdgcn_global_load_lds((__attribute__((address_space(1))) void*)g,
                                   (__attribute__((address_space(3))) void*)l,
                                   16, 0, 0);
}

// ------------- fused pre-pass: x f32->bf16  +  4 weight transposes -------------
__global__ void k_pre(const float* __restrict__ x, u16* __restrict__ x_bf,
                      const float* __restrict__ Wq, const float* __restrict__ Wk,
                      const float* __restrict__ Wv, const float* __restrict__ Wo,
                      u16* __restrict__ Wqt, u16* __restrict__ Wkt,
                      u16* __restrict__ Wvt, u16* __restrict__ Wot) {
  const int bid = blockIdx.x;
  if (bid < 4096) {
    int i = (bid * 256 + threadIdx.x) * 8;
    float4 a = *(const float4*)(x + i);
    float4 b = *(const float4*)(x + i + 4);
    short8 o;
    o[0] = (short)f2b(a.x); o[1] = (short)f2b(a.y);
    o[2] = (short)f2b(a.z); o[3] = (short)f2b(a.w);
    o[4] = (short)f2b(b.x); o[5] = (short)f2b(b.y);
    o[6] = (short)f2b(b.z); o[7] = (short)f2b(b.w);
    *(short8*)(x_bf + i) = o;
    return;
  }
  __shared__ float tile[32][33];
  const int idx = bid - 4096;          // 0..10239
  const int cb = idx % 160;
  const int k0 = (idx / 160) * 32;
  const float* W; u16* Wt; int N, n0;
  if (cb < 64)      { W = Wq; Wt = Wqt; N = 2048; n0 = cb * 32; }
  else if (cb < 80) { W = Wk; Wt = Wkt; N = 512;  n0 = (cb - 64) * 32; }
  else if (cb < 96) { W = Wv; Wt = Wvt; N = 512;  n0 = (cb - 80) * 32; }
  else              { W = Wo; Wt = Wot; N = 2048; n0 = (cb - 96) * 32; }
  const int tx = threadIdx.x & 31, ty = threadIdx.x >> 5;
#pragma unroll
  for (int i = 0; i < 4; i++) {
    int r = ty + i * 8;
    tile[r][tx] = W[(size_t)(k0 + r) * N + n0 + tx];
  }
  __syncthreads();
#pragma unroll
  for (int i = 0; i < 4; i++) {
    int r = ty + i * 8;
    Wt[(size_t)(n0 + r) * 2048 + k0 + tx] = f2b(tile[tx][r]);
  }
}

// ------------- fused QKV GEMM (128x128 tiles, T2 XOR-swizzled LDS) -------------
__global__ __launch_bounds__(256, 3) void k_gemm_qkv(
    const u16* __restrict__ A,
    const u16* __restrict__ Wqt, const u16* __restrict__ Wkt, const u16* __restrict__ Wvt,
    u16* __restrict__ Qout, u16* __restrict__ Kout, u16* __restrict__ Vt,
    float qscale)
{
  __shared__ __attribute__((aligned(16))) u16 lA[128 * 64];
  __shared__ __attribute__((aligned(16))) u16 lB[128 * 64];
  const int K = D_MOD;
  const int tid = threadIdx.x;
  const int lane = tid & 63, w = tid >> 6;
  const int wr = w >> 1, wc = w & 1;
  const int lin = blockIdx.y * 24 + blockIdx.x;
  const int swz = (lin & 7) * 96 + (lin >> 3);
  const int bx = swz % 24;
  const int kind = bx < 16 ? 0 : (bx < 20 ? 1 : 2);
  const int bcol = (kind == 0 ? bx : (bx & 3)) * 128;
  const u16* Bt = kind == 0 ? Wqt : (kind == 1 ? Wkt : Wvt);
  const int brow = (swz / 24) * 128;
  const int lrow = lane >> 3;
  const int l15 = lane & 15, lg = lane >> 4;
  const int l7a = l15 & 7;

  f32x4 acc[4][4] = {};

  for (int kt = 0; kt < K; kt += 64) {
#pragma unroll
    for (int i = 0; i < 4; i++) {
      int row = (w * 4 + i) * 8 + lrow;
      int ch = (lane & 7) ^ (row & 7);
      gload_lds16(A + (size_t)(brow + row) * K + kt + ch * 8, &lA[(w * 4 + i) * 512]);
      gload_lds16(Bt + (size_t)(bcol + row) * K + kt + ch * 8, &lB[(w * 4 + i) * 512]);
    }
    __syncthreads();
#pragma unroll
    for (int kk = 0; kk < 2; kk++) {
      short8 af[4], bf[4];
#pragma unroll
      for (int m = 0; m < 4; m++)
        af[m] = *(const short8*)&lA[(wr * 64 + m * 16 + l15) * 64 + (((kk * 4 + lg) ^ l7a) * 8)];
#pragma unroll
      for (int n = 0; n < 4; n++)
        bf[n] = *(const short8*)&lB[(wc * 64 + n * 16 + l15) * 64 + (((kk * 4 + lg) ^ l7a) * 8)];
#pragma unroll
      for (int m = 0; m < 4; m++)
#pragma unroll
        for (int n = 0; n < 4; n++)
          acc[m][n] = __builtin_amdgcn_mfma_f32_16x16x32_bf16(af[m], bf[n], acc[m][n], 0, 0, 0);
    }
    __syncthreads();
  }

#pragma unroll
  for (int m = 0; m < 4; m++) {
#pragma unroll
    for (int n = 0; n < 4; n++) {
#pragma unroll
      for (int r = 0; r < 4; r++) {
        float v = acc[m][n][r];
        int row = brow + wr * 64 + m * 16 + lg * 4 + r;
        int col = bcol + wc * 64 + n * 16 + l15;
        if (kind == 0) {
          Qout[(size_t)row * (N_HQ * N_HD) + col] = f2b(v * qscale);
        } else if (kind == 1) {
          Kout[(size_t)row * (N_HKV * N_HD) + col] = f2b(v);
        } else { // V^T scatter (natural s order): row = token, col = hkv*128+d
          int bb = row >> 11, s = row & 2047;
          int hkv = col >> 7, d = col & 127;
          Vt[((size_t)((bb * N_HKV + hkv) * N_HD + d)) * S_LEN + s] = f2b(v);
        }
      }
    }
  }
}

// ---------------- O-proj GEMM (128x128 tiles, T2 XOR-swizzled LDS) ----------------
__global__ __launch_bounds__(256, 3) void k_gemm_o(
    const u16* __restrict__ A, const u16* __restrict__ Bt,
    float* __restrict__ Cout, const float* __restrict__ bias,
    int M, int N, int K)
{
  __shared__ __attribute__((aligned(16))) u16 lA[128 * 64];
  __shared__ __attribute__((aligned(16))) u16 lB[128 * 64];
  const int tid = threadIdx.x;
  const int lane = tid & 63, w = tid >> 6;
  const int wr = w >> 1, wc = w & 1;
  const int lin = blockIdx.y * 16 + blockIdx.x;
  const int swz = (lin & 7) * 64 + (lin >> 3);
  const int brow = (swz / 16) * 128, bcol = (swz % 16) * 128;
  const int lrow = lane >> 3;
  const int l15 = lane & 15, lg = lane >> 4;
  const int l7a = l15 & 7;

  f32x4 acc[4][4] = {};

  for (int kt = 0; kt < K; kt += 64) {
#pragma unroll
    for (int i = 0; i < 4; i++) {
      int row = (w * 4 + i) * 8 + lrow;
      int ch = (lane & 7) ^ (row & 7);
      gload_lds16(A + (size_t)(brow + row) * K + kt + ch * 8, &lA[(w * 4 + i) * 512]);
      gload_lds16(Bt + (size_t)(bcol + row) * K + kt + ch * 8, &lB[(w * 4 + i) * 512]);
    }
    __syncthreads();
#pragma unroll
    for (int kk = 0; kk < 2; kk++) {
      short8 af[4], bf[4];
#pragma unroll
      for (int m = 0; m < 4; m++)
        af[m] = *(const short8*)&lA[(wr * 64 + m * 16 + l15) * 64 + (((kk * 4 + lg) ^ l7a) * 8)];
#pragma unroll
      for (int n = 0; n < 4; n++)
        bf[n] = *(const short8*)&lB[(wc * 64 + n * 16 + l15) * 64 + (((kk * 4 + lg) ^ l7a) * 8)];
#pragma unroll
      for (int m = 0; m < 4; m++)
#pragma unroll
        for (int n = 0; n < 4; n++)
          acc[m][n] = __builtin_amdgcn_mfma_f32_16x16x32_bf16(af[m], bf[n], acc[m][n], 0, 0, 0);
    }
    __syncthreads();
  }

#pragma unroll
  for (int m = 0; m < 4; m++) {
#pragma unroll
    for (int n = 0; n < 4; n++) {
#pragma unroll
      for (int r = 0; r < 4; r++) {
        int row = brow + wr * 64 + m * 16 + lg * 4 + r;
        int col = bcol + wc * 64 + n * 16 + l15;
        Cout[(size_t)row * N + col] = acc[m][n][r] + bias[col];
      }
    }
  }
}

// ---------------- flash attention v11: T14 single-buffer, 3 blocks/CU ----------------
// 32KB LDS; launch_bounds(256,3) -> VGPR cap ~170 (fits ~155 need, NO spill — R16's
// (256,4)/128-cap spilled 884MB to scratch). 3 blocks/CU = 12 waves/CU vs v9's 8.
__global__ __launch_bounds__(256, 3) void k_attn(
    const u16* __restrict__ Q,   // [B*S, HQ*HD], pre-scaled by SCALE*log2e
    const u16* __restrict__ Kb,  // [B*S, HKV*HD]
    const u16* __restrict__ Vt,  // [B, HKV, HD, S] natural s order
    u16* __restrict__ O)         // [B*S, HQ*HD]
{
  __shared__ __attribute__((aligned(16))) u16 lK[64 * 128];   // 16KB
  __shared__ __attribute__((aligned(16))) u16 lV[128 * 64];   // 16KB (V^T)
  const int lane = threadIdx.x & 63, w = threadIdx.x >> 6;
  const int lin = blockIdx.z * 256 + blockIdx.y * 16 + blockIdx.x;
  const int swz = (lin & 7) * 64 + (lin >> 3);
  const int qt = swz & 15, h = (swz >> 4) & 15, b = swz >> 8;
  const int hkv = h >> 2;
  const int qbase = qt * 128 + w * 32;
  const int l15 = lane & 15, lg = lane >> 4;
  const int l7 = lane & 7, l3 = lane >> 3;

  const u16* kbp = Kb + (size_t)(b * S_LEN) * (N_HKV * N_HD) + hkv * N_HD;
  const u16* vbp = Vt + (size_t)((b * N_HKV + hkv) * N_HD) * S_LEN;

  short8 qf[2][4];
#pragma unroll
  for (int s = 0; s < 2; s++) {
    const u16* qptr = Q + (size_t)(b * S_LEN + qbase + s * 16 + l15) * (N_HQ * N_HD) + h * N_HD + lg * 8;
#pragma unroll
    for (int kk = 0; kk < 4; kk++) qf[s][kk] = *(const short8*)(qptr + kk * 32);
  }

  f32x4 acc_o[2][8] = {};
  f32x4 acc_ls[2] = {};
  short8 vone;
#pragma unroll
  for (int j = 0; j < 8; j++) vone[j] = (short)0x3F80; // bf16 1.0

  short8 kreg[4], vreg[4];

#define LOADREGS(ktv) do {                                                           \
    _Pragma("unroll")                                                                \
    for (int i = 0; i < 4; i++) {                                                    \
      int kr = i * 16 + w * 4 + lg;                                                  \
      int sx = (kr & 3) ^ (((kr >> 3) & 3) << 1);                                    \
      kreg[i] = *(const short8*)(kbp + (size_t)((ktv) + kr) * (N_HKV * N_HD) + (l15 ^ sx) * 8); \
      int vr = i * 32 + w * 8 + l3;                                                  \
      vreg[i] = *(const short8*)(vbp + (size_t)vr * S_LEN + (ktv) + (l7 ^ (vr & 7)) * 8);       \
    } } while (0)

#define WRITEREGS() do {                                                             \
    _Pragma("unroll")                                                                \
    for (int i = 0; i < 4; i++) {                                                    \
      *(short8*)&lK[(i * 16 + w * 4) * 128 + lane * 8] = kreg[i];                    \
      *(short8*)&lV[(i * 32 + w * 8) * 64 + lane * 8] = vreg[i];                     \
    } } while (0)

  LOADREGS(0);
  WRITEREGS();
  __syncthreads();

  const int sxr = (l15 & 3) ^ (((l15 >> 2) & 3) << 1); // sxk(sigma_nf(l15)) (nf-indep)
  const int NT = S_LEN / 64;
  for (int it = 0; it < NT; ++it) {
    if (it + 1 < NT) LOADREGS((it + 1) * 64);   // issue early; lands during compute

    // ---- sc = K sigma-rows x Q  -> D[key][q]  (kf read once, shared by both q-sets) ----
    f32x4 sc[2][4] = {};
    __builtin_amdgcn_s_setprio(1);
#pragma unroll
    for (int nf = 0; nf < 4; nf++) {
      int krow = (nf >> 1) * 32 + ((l15 >> 2) * 8) + ((nf & 1) * 4) + (l15 & 3);
      const u16* kro = &lK[krow * 128];
#pragma unroll
      for (int kk = 0; kk < 4; kk++) {
        short8 kf = *(const short8*)&kro[(((kk * 4 + lg) ^ sxr) * 8)];
#pragma unroll
        for (int s = 0; s < 2; s++)
          sc[s][nf] = __builtin_amdgcn_mfma_f32_16x16x32_bf16(kf, qf[s][kk], sc[s][nf], 0, 0, 0);
      }
    }
    __builtin_amdgcn_s_setprio(0);

    // ---- P = exp2(sc), packed in-lane via round-half-up + v_perm ----
    short8 pf[2][2];
#pragma unroll
    for (int s = 0; s < 2; s++)
#pragma unroll
      for (int p2 = 0; p2 < 2; p2++) {
        union { short8 s8; uint32_t w4[4]; } u;
#pragma unroll
        for (int j = 0; j < 4; j++) {
          float lo = __builtin_amdgcn_exp2f(sc[s][p2 * 2 + (j >> 1)][(j & 1) * 2]);
          float hi = __builtin_amdgcn_exp2f(sc[s][p2 * 2 + (j >> 1)][(j & 1) * 2 + 1]);
          u.w4[j] = pack2_rhu(lo, hi);
        }
        pf[s][p2] = u.s8;
      }

    // ---- rowsum + PV (setprio cluster) ----
    __builtin_amdgcn_s_setprio(1);
#pragma unroll
    for (int s = 0; s < 2; s++)
#pragma unroll
      for (int p2 = 0; p2 < 2; p2++)
        acc_ls[s] = __builtin_amdgcn_mfma_f32_16x16x32_bf16(pf[s][p2], vone, acc_ls[s], 0, 0, 0);

#pragma unroll
    for (int nc = 0; nc < 8; nc++) {
      int vrow = nc * 16 + l15;
      const u16* vro = &lV[vrow * 64];
#pragma unroll
      for (int p2 = 0; p2 < 2; p2++) {
        short8 vf = *(const short8*)&vro[(((p2 * 4 + lg) ^ (vrow & 7)) * 8)];
#pragma unroll
        for (int s = 0; s < 2; s++)
          acc_o[s][nc] = __builtin_amdgcn_mfma_f32_16x16x32_bf16(pf[s][p2], vf, acc_o[s][nc], 0, 0, 0);
      }
    }
    __builtin_amdgcn_s_setprio(0);

    __syncthreads();                 // A: all waves done reading lK/lV
    if (it + 1 < NT) WRITEREGS();    // vmcnt waits auto-inserted on reg use
    __syncthreads();                 // B: new tile visible to all waves
  }
#undef LOADREGS
#undef WRITEREGS

#pragma unroll
  for (int s = 0; s < 2; s++)
#pragma unroll
    for (int r = 0; r < 4; r++) {
      float inv = 1.f / acc_ls[s][r];
      size_t row = (size_t)(b * S_LEN + qbase + s * 16 + lg * 4 + r);
#pragma unroll
      for (int nc = 0; nc < 8; nc++)
        O[row * (N_HQ * N_HD) + h * N_HD + nc * 16 + l15] = f2b(acc_o[s][nc][r] * inv);
    }
}

// ---------------- launcher ----------------
extern "C" void kernel_launch(void* const* d_in, const int* in_sizes, int n_in,
                              void* d_out, int out_size, void* d_ws, size_t ws_size,
                              hipStream_t stream) {
  const float* x  = (const float*)d_in[0];
  const float* Wq = (const float*)d_in[1];
  const float* Wk = (const float*)d_in[2];
  const float* Wv = (const float*)d_in[3];
  const float* Wo = (const float*)d_in[4];
  const float* bo = (const float*)d_in[5];
  float* out = (float*)d_out;

  char* ws = (char*)d_ws;
  u16* x_bf = (u16*)(ws + 0);           // 8388608 elems
  u16* Wqt  = (u16*)(ws + 16777216);    // 4194304 elems
  u16* Wkt  = (u16*)(ws + 25165824);    // 1048576 elems
  u16* Wvt  = (u16*)(ws + 27262976);    // 1048576 elems
  u16* Wot  = (u16*)(ws + 29360128);    // 4194304 elems
  u16* Qb   = (u16*)(ws + 37748736);    // 8388608 elems
  u16* Kbuf = (u16*)(ws + 54525952);    // 2097152 elems
  u16* Vt   = (u16*)(ws + 58720256);    // 2097152 elems
  u16* AO   = (u16*)(ws + 0);           // 8388608 elems (reuse of x_bf)

  // fused pre-pass: x convert (4096 blocks) + weight transposes (10240 blocks)
  k_pre<<<14336, 256, 0, stream>>>(x, x_bf, Wq, Wk, Wv, Wo, Wqt, Wkt, Wvt, Wot);

  const float qscale = 1.4426950408889634f / sqrtf((float)N_HD); // SCALE * log2(e)

  // fused Q/K/V projections (128x128 tiles, 3 blocks/CU)
  k_gemm_qkv<<<dim3(24, 32), 256, 0, stream>>>(
      x_bf, Wqt, Wkt, Wvt, Qb, Kbuf, Vt, qscale);

  // attention
  k_attn<<<dim3(S_LEN / 128, N_HQ, B_N), 256, 0, stream>>>(Qb, Kbuf, Vt, AO);

  // out = AO @ Wo + bo  (f32)
  k_gemm_o<<<dim3(16, 32), 256, 0, stream>>>(
      AO, Wot, out, bo, B_N * S_LEN, D_MOD, N_HQ * N_HD);
}

// Round 18
// 180.555 us; speedup vs baseline: 2.5075x; 1.4740x over previous
//
#include <hip/hip_runtime.h>
#include <hip/hip_bf16.h>
#include <stdint.h>

typedef unsigned short u16;
typedef __attribute__((ext_vector_type(8))) short short8;
typedef __attribute__((ext_vector_type(4))) float f32x4;

#define B_N   2
#define S_LEN 2048
#define D_MOD 2048
#define N_HQ  16
#define N_HKV 4
#define N_HD  128
// G = 4

__device__ __forceinline__ u16 f2b(float f) {
  union { float f; uint32_t u; } v; v.f = f;
  uint32_t r = v.u + 0x7fffu + ((v.u >> 16) & 1u);
  return (u16)(r >> 16);
}

// round-half-up bf16 pair pack: hi16(a+0x8000) in [15:0], hi16(b+0x8000) in [31:16]
// (<=0.5 ulp like RNE; NOT the truncating v_cvt_pk_bf16_f32 — R10 failure)
__device__ __forceinline__ uint32_t pack2_rhu(float a, float b) {
  union { float f; uint32_t u; } va, vb;
  va.f = a; vb.f = b;
  return __builtin_amdgcn_perm(vb.u + 0x8000u, va.u + 0x8000u, 0x07060302u);
}

__device__ __forceinline__ void gload_lds16(const void* g, void* l) {
  __builtin_amdgcn_global_load_lds((__attribute__((address_space(1))) void*)g,
                                   (__attribute__((address_space(3))) void*)l,
                                   16, 0, 0);
}

// ------------- fused pre-pass: x f32->bf16  +  4 weight transposes -------------
__global__ void k_pre(const float* __restrict__ x, u16* __restrict__ x_bf,
                      const float* __restrict__ Wq, const float* __restrict__ Wk,
                      const float* __restrict__ Wv, const float* __restrict__ Wo,
                      u16* __restrict__ Wqt, u16* __restrict__ Wkt,
                      u16* __restrict__ Wvt, u16* __restrict__ Wot) {
  const int bid = blockIdx.x;
  if (bid < 4096) {
    int i = (bid * 256 + threadIdx.x) * 8;
    float4 a = *(const float4*)(x + i);
    float4 b = *(const float4*)(x + i + 4);
    short8 o;
    o[0] = (short)f2b(a.x); o[1] = (short)f2b(a.y);
    o[2] = (short)f2b(a.z); o[3] = (short)f2b(a.w);
    o[4] = (short)f2b(b.x); o[5] = (short)f2b(b.y);
    o[6] = (short)f2b(b.z); o[7] = (short)f2b(b.w);
    *(short8*)(x_bf + i) = o;
    return;
  }
  __shared__ float tile[32][33];
  const int idx = bid - 4096;          // 0..10239
  const int cb = idx % 160;
  const int k0 = (idx / 160) * 32;
  const float* W; u16* Wt; int N, n0;
  if (cb < 64)      { W = Wq; Wt = Wqt; N = 2048; n0 = cb * 32; }
  else if (cb < 80) { W = Wk; Wt = Wkt; N = 512;  n0 = (cb - 64) * 32; }
  else if (cb < 96) { W = Wv; Wt = Wvt; N = 512;  n0 = (cb - 80) * 32; }
  else              { W = Wo; Wt = Wot; N = 2048; n0 = (cb - 96) * 32; }
  const int tx = threadIdx.x & 31, ty = threadIdx.x >> 5;
#pragma unroll
  for (int i = 0; i < 4; i++) {
    int r = ty + i * 8;
    tile[r][tx] = W[(size_t)(k0 + r) * N + n0 + tx];
  }
  __syncthreads();
#pragma unroll
  for (int i = 0; i < 4; i++) {
    int r = ty + i * 8;
    Wt[(size_t)(n0 + r) * 2048 + k0 + tx] = f2b(tile[tx][r]);
  }
}

// ------------- fused QKV GEMM (128x128 tiles, T2 XOR-swizzled LDS) -------------
__global__ __launch_bounds__(256, 3) void k_gemm_qkv(
    const u16* __restrict__ A,
    const u16* __restrict__ Wqt, const u16* __restrict__ Wkt, const u16* __restrict__ Wvt,
    u16* __restrict__ Qout, u16* __restrict__ Kout, u16* __restrict__ Vt,
    float qscale)
{
  __shared__ __attribute__((aligned(16))) u16 lA[128 * 64];
  __shared__ __attribute__((aligned(16))) u16 lB[128 * 64];
  const int K = D_MOD;
  const int tid = threadIdx.x;
  const int lane = tid & 63, w = tid >> 6;
  const int wr = w >> 1, wc = w & 1;
  const int lin = blockIdx.y * 24 + blockIdx.x;
  const int swz = (lin & 7) * 96 + (lin >> 3);
  const int bx = swz % 24;
  const int kind = bx < 16 ? 0 : (bx < 20 ? 1 : 2);
  const int bcol = (kind == 0 ? bx : (bx & 3)) * 128;
  const u16* Bt = kind == 0 ? Wqt : (kind == 1 ? Wkt : Wvt);
  const int brow = (swz / 24) * 128;
  const int lrow = lane >> 3;
  const int l15 = lane & 15, lg = lane >> 4;
  const int l7a = l15 & 7;

  f32x4 acc[4][4] = {};

  for (int kt = 0; kt < K; kt += 64) {
#pragma unroll
    for (int i = 0; i < 4; i++) {
      int row = (w * 4 + i) * 8 + lrow;
      int ch = (lane & 7) ^ (row & 7);
      gload_lds16(A + (size_t)(brow + row) * K + kt + ch * 8, &lA[(w * 4 + i) * 512]);
      gload_lds16(Bt + (size_t)(bcol + row) * K + kt + ch * 8, &lB[(w * 4 + i) * 512]);
    }
    __syncthreads();
#pragma unroll
    for (int kk = 0; kk < 2; kk++) {
      short8 af[4], bf[4];
#pragma unroll
      for (int m = 0; m < 4; m++)
        af[m] = *(const short8*)&lA[(wr * 64 + m * 16 + l15) * 64 + (((kk * 4 + lg) ^ l7a) * 8)];
#pragma unroll
      for (int n = 0; n < 4; n++)
        bf[n] = *(const short8*)&lB[(wc * 64 + n * 16 + l15) * 64 + (((kk * 4 + lg) ^ l7a) * 8)];
#pragma unroll
      for (int m = 0; m < 4; m++)
#pragma unroll
        for (int n = 0; n < 4; n++)
          acc[m][n] = __builtin_amdgcn_mfma_f32_16x16x32_bf16(af[m], bf[n], acc[m][n], 0, 0, 0);
    }
    __syncthreads();
  }

#pragma unroll
  for (int m = 0; m < 4; m++) {
#pragma unroll
    for (int n = 0; n < 4; n++) {
#pragma unroll
      for (int r = 0; r < 4; r++) {
        float v = acc[m][n][r];
        int row = brow + wr * 64 + m * 16 + lg * 4 + r;
        int col = bcol + wc * 64 + n * 16 + l15;
        if (kind == 0) {
          Qout[(size_t)row * (N_HQ * N_HD) + col] = f2b(v * qscale);
        } else if (kind == 1) {
          Kout[(size_t)row * (N_HKV * N_HD) + col] = f2b(v);
        } else { // V^T scatter (natural s order): row = token, col = hkv*128+d
          int bb = row >> 11, s = row & 2047;
          int hkv = col >> 7, d = col & 127;
          Vt[((size_t)((bb * N_HKV + hkv) * N_HD + d)) * S_LEN + s] = f2b(v);
        }
      }
    }
  }
}

// ---------------- O-proj GEMM (128x128 tiles, T2 XOR-swizzled LDS) ----------------
__global__ __launch_bounds__(256, 3) void k_gemm_o(
    const u16* __restrict__ A, const u16* __restrict__ Bt,
    float* __restrict__ Cout, const float* __restrict__ bias,
    int M, int N, int K)
{
  __shared__ __attribute__((aligned(16))) u16 lA[128 * 64];
  __shared__ __attribute__((aligned(16))) u16 lB[128 * 64];
  const int tid = threadIdx.x;
  const int lane = tid & 63, w = tid >> 6;
  const int wr = w >> 1, wc = w & 1;
  const int lin = blockIdx.y * 16 + blockIdx.x;
  const int swz = (lin & 7) * 64 + (lin >> 3);
  const int brow = (swz / 16) * 128, bcol = (swz % 16) * 128;
  const int lrow = lane >> 3;
  const int l15 = lane & 15, lg = lane >> 4;
  const int l7a = l15 & 7;

  f32x4 acc[4][4] = {};

  for (int kt = 0; kt < K; kt += 64) {
#pragma unroll
    for (int i = 0; i < 4; i++) {
      int row = (w * 4 + i) * 8 + lrow;
      int ch = (lane & 7) ^ (row & 7);
      gload_lds16(A + (size_t)(brow + row) * K + kt + ch * 8, &lA[(w * 4 + i) * 512]);
      gload_lds16(Bt + (size_t)(bcol + row) * K + kt + ch * 8, &lB[(w * 4 + i) * 512]);
    }
    __syncthreads();
#pragma unroll
    for (int kk = 0; kk < 2; kk++) {
      short8 af[4], bf[4];
#pragma unroll
      for (int m = 0; m < 4; m++)
        af[m] = *(const short8*)&lA[(wr * 64 + m * 16 + l15) * 64 + (((kk * 4 + lg) ^ l7a) * 8)];
#pragma unroll
      for (int n = 0; n < 4; n++)
        bf[n] = *(const short8*)&lB[(wc * 64 + n * 16 + l15) * 64 + (((kk * 4 + lg) ^ l7a) * 8)];
#pragma unroll
      for (int m = 0; m < 4; m++)
#pragma unroll
        for (int n = 0; n < 4; n++)
          acc[m][n] = __builtin_amdgcn_mfma_f32_16x16x32_bf16(af[m], bf[n], acc[m][n], 0, 0, 0);
    }
    __syncthreads();
  }

#pragma unroll
  for (int m = 0; m < 4; m++) {
#pragma unroll
    for (int n = 0; n < 4; n++) {
#pragma unroll
      for (int r = 0; r < 4; r++) {
        int row = brow + wr * 64 + m * 16 + lg * 4 + r;
        int col = bcol + wc * 64 + n * 16 + l15;
        Cout[(size_t)row * N + col] = acc[m][n][r] + bias[col];
      }
    }
  }
}

// ---------------- flash attention v9: dbuf gload_lds, rhu+perm pack (R15-proven) ----------------
__global__ __launch_bounds__(256, 2) void k_attn(
    const u16* __restrict__ Q,   // [B*S, HQ*HD], pre-scaled by SCALE*log2e
    const u16* __restrict__ Kb,  // [B*S, HKV*HD]
    const u16* __restrict__ Vt,  // [B, HKV, HD, S] natural s order
    u16* __restrict__ O)         // [B*S, HQ*HD]
{
  __shared__ __attribute__((aligned(16))) u16 lK[2][64 * 128];   // 16KB x2
  __shared__ __attribute__((aligned(16))) u16 lV[2][128 * 64];   // 16KB x2 (V^T)
  const int lane = threadIdx.x & 63, w = threadIdx.x >> 6;
  const int lin = blockIdx.z * 256 + blockIdx.y * 16 + blockIdx.x;
  const int swz = (lin & 7) * 64 + (lin >> 3);
  const int qt = swz & 15, h = (swz >> 4) & 15, b = swz >> 8;
  const int hkv = h >> 2;
  const int qbase = qt * 128 + w * 32;
  const int l15 = lane & 15, lg = lane >> 4;
  const int l7 = lane & 7, l3 = lane >> 3;

  const u16* kbp = Kb + (size_t)(b * S_LEN) * (N_HKV * N_HD) + hkv * N_HD;
  const u16* vbp = Vt + (size_t)((b * N_HKV + hkv) * N_HD) * S_LEN;

  short8 qf[2][4];
#pragma unroll
  for (int s = 0; s < 2; s++) {
    const u16* qptr = Q + (size_t)(b * S_LEN + qbase + s * 16 + l15) * (N_HQ * N_HD) + h * N_HD + lg * 8;
#pragma unroll
    for (int kk = 0; kk < 4; kk++) qf[s][kk] = *(const short8*)(qptr + kk * 32);
  }

  f32x4 acc_o[2][8] = {};
  f32x4 acc_ls[2] = {};
  short8 vone;
#pragma unroll
  for (int j = 0; j < 8; j++) vone[j] = (short)0x3F80; // bf16 1.0

#define STAGE(bufi, ktv) do {                                                        \
    _Pragma("unroll")                                                                \
    for (int i = 0; i < 4; i++) {                                                    \
      int kr = i * 16 + w * 4 + lg;                                                  \
      int sx = (kr & 3) ^ (((kr >> 3) & 3) << 1);                                    \
      gload_lds16(kbp + (size_t)((ktv) + kr) * (N_HKV * N_HD) + ((l15 ^ sx)) * 8,    \
                  &lK[bufi][(i * 16 + w * 4) * 128]);                                \
      int vr = i * 32 + w * 8 + l3;                                                  \
      gload_lds16(vbp + (size_t)vr * S_LEN + (ktv) + ((l7 ^ (vr & 7))) * 8,          \
                  &lV[bufi][(i * 32 + w * 8) * 64]);                                 \
    } } while (0)

  STAGE(0, 0);
  __syncthreads();

  const int sxr = (l15 & 3) ^ (((l15 >> 2) & 3) << 1); // sxk(sigma_nf(l15)) (nf-indep)
  const int NT = S_LEN / 64;
  int buf = 0;
  for (int it = 0; it < NT; ++it) {
    if (it + 1 < NT) STAGE(buf ^ 1, (it + 1) * 64);

    // ---- sc = K sigma-rows x Q  -> D[key][q]  (kf read once, shared by both q-sets) ----
    f32x4 sc[2][4] = {};
    __builtin_amdgcn_s_setprio(1);
#pragma unroll
    for (int nf = 0; nf < 4; nf++) {
      int krow = (nf >> 1) * 32 + ((l15 >> 2) * 8) + ((nf & 1) * 4) + (l15 & 3);
      const u16* kro = &lK[buf][krow * 128];
#pragma unroll
      for (int kk = 0; kk < 4; kk++) {
        short8 kf = *(const short8*)&kro[(((kk * 4 + lg) ^ sxr) * 8)];
#pragma unroll
        for (int s = 0; s < 2; s++)
          sc[s][nf] = __builtin_amdgcn_mfma_f32_16x16x32_bf16(kf, qf[s][kk], sc[s][nf], 0, 0, 0);
      }
    }
    __builtin_amdgcn_s_setprio(0);

    // ---- P = exp2(sc), packed in-lane via round-half-up + v_perm (3 VALU/pair) ----
    short8 pf[2][2];
#pragma unroll
    for (int s = 0; s < 2; s++)
#pragma unroll
      for (int p2 = 0; p2 < 2; p2++) {
        union { short8 s8; uint32_t w4[4]; } u;
#pragma unroll
        for (int j = 0; j < 4; j++) {
          float lo = __builtin_amdgcn_exp2f(sc[s][p2 * 2 + (j >> 1)][(j & 1) * 2]);
          float hi = __builtin_amdgcn_exp2f(sc[s][p2 * 2 + (j >> 1)][(j & 1) * 2 + 1]);
          u.w4[j] = pack2_rhu(lo, hi);
        }
        pf[s][p2] = u.s8;
      }

    // ---- rowsum + PV (setprio cluster) ----
    __builtin_amdgcn_s_setprio(1);
#pragma unroll
    for (int s = 0; s < 2; s++)
#pragma unroll
      for (int p2 = 0; p2 < 2; p2++)
        acc_ls[s] = __builtin_amdgcn_mfma_f32_16x16x32_bf16(pf[s][p2], vone, acc_ls[s], 0, 0, 0);

#pragma unroll
    for (int nc = 0; nc < 8; nc++) {
      int vrow = nc * 16 + l15;
      const u16* vro = &lV[buf][vrow * 64];
#pragma unroll
      for (int p2 = 0; p2 < 2; p2++) {
        short8 vf = *(const short8*)&vro[(((p2 * 4 + lg) ^ (vrow & 7)) * 8)];
#pragma unroll
        for (int s = 0; s < 2; s++)
          acc_o[s][nc] = __builtin_amdgcn_mfma_f32_16x16x32_bf16(pf[s][p2], vf, acc_o[s][nc], 0, 0, 0);
      }
    }
    __builtin_amdgcn_s_setprio(0);

    __syncthreads();   // drains vmcnt(0): next buf complete; all waves done with cur buf
    buf ^= 1;
  }
#undef STAGE

#pragma unroll
  for (int s = 0; s < 2; s++)
#pragma unroll
    for (int r = 0; r < 4; r++) {
      float inv = 1.f / acc_ls[s][r];
      size_t row = (size_t)(b * S_LEN + qbase + s * 16 + lg * 4 + r);
#pragma unroll
      for (int nc = 0; nc < 8; nc++)
        O[row * (N_HQ * N_HD) + h * N_HD + nc * 16 + l15] = f2b(acc_o[s][nc][r] * inv);
    }
}

// ---------------- launcher ----------------
extern "C" void kernel_launch(void* const* d_in, const int* in_sizes, int n_in,
                              void* d_out, int out_size, void* d_ws, size_t ws_size,
                              hipStream_t stream) {
  const float* x  = (const float*)d_in[0];
  const float* Wq = (const float*)d_in[1];
  const float* Wk = (const float*)d_in[2];
  const float* Wv = (const float*)d_in[3];
  const float* Wo = (const float*)d_in[4];
  const float* bo = (const float*)d_in[5];
  float* out = (float*)d_out;

  char* ws = (char*)d_ws;
  u16* x_bf = (u16*)(ws + 0);           // 8388608 elems
  u16* Wqt  = (u16*)(ws + 16777216);    // 4194304 elems
  u16* Wkt  = (u16*)(ws + 25165824);    // 1048576 elems
  u16* Wvt  = (u16*)(ws + 27262976);    // 1048576 elems
  u16* Wot  = (u16*)(ws + 29360128);    // 4194304 elems
  u16* Qb   = (u16*)(ws + 37748736);    // 8388608 elems
  u16* Kbuf = (u16*)(ws + 54525952);    // 2097152 elems
  u16* Vt   = (u16*)(ws + 58720256);    // 2097152 elems
  u16* AO   = (u16*)(ws + 0);           // 8388608 elems (reuse of x_bf)

  // fused pre-pass: x convert (4096 blocks) + weight transposes (10240 blocks)
  k_pre<<<14336, 256, 0, stream>>>(x, x_bf, Wq, Wk, Wv, Wo, Wqt, Wkt, Wvt, Wot);

  const float qscale = 1.4426950408889634f / sqrtf((float)N_HD); // SCALE * log2(e)

  // fused Q/K/V projections (128x128 tiles, 3 blocks/CU)
  k_gemm_qkv<<<dim3(24, 32), 256, 0, stream>>>(
      x_bf, Wqt, Wkt, Wvt, Qb, Kbuf, Vt, qscale);

  // attention
  k_attn<<<dim3(S_LEN / 128, N_HQ, B_N), 256, 0, stream>>>(Qb, Kbuf, Vt, AO);

  // out = AO @ Wo + bo  (f32)
  k_gemm_o<<<dim3(16, 32), 256, 0, stream>>>(
      AO, Wot, out, bo, B_N * S_LEN, D_MOD, N_HQ * N_HD);
}